// Round 1
// baseline (295.738 us; speedup 1.0000x reference)
//
#include <hip/hip_runtime.h>
#include <stdint.h>

#define Bdim 64
#define Tdim 8192
#define MAXP 32
#define NW (Tdim / 64)        // 128 bitmask words per row
#define VOCAB_WORDS_MAX 1024  // >= ceil(50257/64) = 786

// ---------------------------------------------------------------------------
// Kernel 1: detect whether the bool tables are stored as uint8 (raw numpy
// bool, 1 byte/elem) or int32 (widened). If any 32-bit word of is_punct
// exceeds 1, bytes are packed -> uint8 layout.
// ---------------------------------------------------------------------------
__global__ void detect_layout_kernel(const int* __restrict__ p, int nwords,
                                     unsigned long long* __restrict__ flag) {
    __shared__ int s_max;
    if (threadIdx.x == 0) s_max = 0;
    __syncthreads();
    int m = 0;
    for (int i = threadIdx.x; i < nwords; i += blockDim.x) {
        int v = p[i];
        if (v < 0) v = 2;          // any negative word -> definitely packed bytes
        if (v > m) m = v;
    }
    atomicMax(&s_max, m);
    __syncthreads();
    if (threadIdx.x == 0) *flag = (s_max > 1) ? 1ull : 0ull;
}

// ---------------------------------------------------------------------------
// Kernel 2: canonicalize both bool tables into bitmasks (1 bit / token).
// ---------------------------------------------------------------------------
__global__ void pack_bits_kernel(const void* __restrict__ punct,
                                 const void* __restrict__ abbr,
                                 int vocab,
                                 const unsigned long long* __restrict__ flag,
                                 unsigned long long* __restrict__ pbits,
                                 unsigned long long* __restrict__ abits,
                                 int nwords) {
    int w = blockIdx.x * blockDim.x + threadIdx.x;
    if (w >= nwords) return;
    bool u8 = (*flag != 0ull);
    unsigned long long pw = 0ull, aw = 0ull;
    int base = w << 6;
    for (int j = 0; j < 64; ++j) {
        int tok = base + j;
        if (tok >= vocab) break;
        bool pv, av;
        if (u8) {
            pv = ((const uint8_t*)punct)[tok] != 0;
            av = ((const uint8_t*)abbr)[tok] != 0;
        } else {
            pv = ((const int*)punct)[tok] != 0;
            av = ((const int*)abbr)[tok] != 0;
        }
        if (pv) pw |= 1ull << j;
        if (av) aw |= 1ull << j;
    }
    pbits[w] = pw;
    abits[w] = aw;
}

// ---------------------------------------------------------------------------
// Kernel 3: one block per batch row.
//   Phase 1: compute base_end bitmask (ballot) + last_real (atomicMax).
//   Phase 2: thread 0 jumps boundary-to-boundary:
//            nb = min(nextSetBit(base_end, lb+1), lb+32, last_real)
//   Phase 3: word-level exclusive prefix of is_end popcounts.
//   Phase 4: all threads emit phrase_id, mask/token_idx scatter, end_pos.
// ---------------------------------------------------------------------------
__global__ __launch_bounds__(256) void phrase_main_kernel(
    const int* __restrict__ ids,
    const unsigned long long* __restrict__ pbits,
    const unsigned long long* __restrict__ abits,
    int* __restrict__ out_mask,   // [B, T, 32] (0/1)
    int* __restrict__ out_idx,    // [B, T, 32]
    int* __restrict__ out_end,    // [B, T]   (pre-filled -1)
    int* __restrict__ out_pid)    // [B, T]
{
    __shared__ unsigned long long base_bits[NW];
    __shared__ unsigned long long end_bits[NW];
    __shared__ unsigned short boundaries[Tdim];
    __shared__ int wprefix[NW];
    __shared__ int s_last_real;
    __shared__ int s_nb;

    const int b = blockIdx.x;
    const int* __restrict__ row = ids + (size_t)b * Tdim;
    const int tid = threadIdx.x;
    const int lane = tid & 63;
    const int wv = tid >> 6;

    if (tid == 0) s_last_real = -1;
    if (tid < NW) end_bits[tid] = 0ull;
    __syncthreads();

    // ---- Phase 1: base_end bits + last_real ----
    int lmax = -1;
    for (int k = 0; k < Tdim / 256; ++k) {
        int t = k * 256 + tid;
        int id = row[t];
        bool real = (id != 0);
        bool punct = (pbits[id >> 6] >> (id & 63)) & 1ull;
        bool abbr = false;
        if (t > 0) {
            int pv = row[t - 1];
            abbr = (abits[pv >> 6] >> (pv & 63)) & 1ull;
        }
        bool be = punct && !abbr && real;
        unsigned long long bal = __ballot(be);
        if (lane == 0) base_bits[k * 4 + wv] = bal;
        if (real) lmax = t;
    }
    atomicMax(&s_last_real, lmax);
    __syncthreads();

    // ---- Phase 2+3: boundary walk (thread 0) + word prefix ----
    if (tid == 0) {
        const int last_real = s_last_real;
        int nb = 0;
        int lb = -1;
        while (lb < last_real) {
            int s = lb + 1;
            int ne;
            {
                int w = s >> 6;
                unsigned long long word = base_bits[w] & (~0ull << (s & 63));
                while (word == 0ull && ++w < NW) word = base_bits[w];
                ne = (w < NW) ? ((w << 6) + __builtin_ctzll(word)) : (1 << 30);
            }
            int cand = ne;
            if (lb + MAXP < cand) cand = lb + MAXP;
            if (last_real < cand) cand = last_real;
            boundaries[nb++] = (unsigned short)cand;
            end_bits[cand >> 6] |= 1ull << (cand & 63);
            lb = cand;
        }
        s_nb = nb;
        int run = 0;
        for (int w = 0; w < NW; ++w) {
            wprefix[w] = run;
            run += __builtin_popcountll(end_bits[w]);
        }
    }
    __syncthreads();

    // ---- Phase 4: outputs ----
    const int last_real = s_last_real;
    const int nb = s_nb;
    const size_t rowbase = (size_t)b * Tdim;
    for (int k = 0; k < Tdim / 256; ++k) {
        int t = k * 256 + tid;
        unsigned long long w = end_bits[t >> 6];
        int pid = wprefix[t >> 6] +
                  __builtin_popcountll(w & ((1ull << (t & 63)) - 1ull));
        out_pid[rowbase + t] = pid;
        if (t <= last_real) {
            int first = (pid == 0) ? 0 : ((int)boundaries[pid - 1] + 1);
            int slot = t - first;                    // guaranteed 0..31
            size_t o = ((rowbase + (size_t)pid) << 5) + (size_t)slot;
            out_mask[o] = 1;
            out_idx[o] = t;
        }
    }
    for (int p = tid; p < nb; p += 256) {
        out_end[rowbase + p] = (int)boundaries[p];
    }
}

// ---------------------------------------------------------------------------
extern "C" void kernel_launch(void* const* d_in, const int* in_sizes, int n_in,
                              void* d_out, int out_size, void* d_ws, size_t ws_size,
                              hipStream_t stream) {
    const int* ids = (const int*)d_in[0];
    const void* punct = d_in[1];
    const void* abbr = d_in[2];
    const int vocab = in_sizes[1];

    int* out = (int*)d_out;
    const size_t maskN = (size_t)Bdim * Tdim * MAXP;   // 16,777,216
    int* out_mask = out;
    int* out_idx  = out + maskN;
    int* out_end  = out + 2 * maskN;
    int* out_pid  = out + 2 * maskN + (size_t)Bdim * Tdim;

    unsigned long long* flag  = (unsigned long long*)d_ws;
    unsigned long long* pbits = (unsigned long long*)((char*)d_ws + 64);
    unsigned long long* abits = pbits + VOCAB_WORDS_MAX;

    // Bulk-fill the sparse outputs.
    hipMemsetAsync(out_mask, 0, 2 * maskN * sizeof(int), stream);            // mask+idx = 0
    hipMemsetAsync(out_end, 0xFF, (size_t)Bdim * Tdim * sizeof(int), stream); // end_pos = -1

    detect_layout_kernel<<<1, 256, 0, stream>>>((const int*)punct, vocab / 4, flag);

    const int nwords = (vocab + 63) / 64;
    pack_bits_kernel<<<(nwords + 255) / 256, 256, 0, stream>>>(
        punct, abbr, vocab, flag, pbits, abits, nwords);

    phrase_main_kernel<<<Bdim, 256, 0, stream>>>(
        ids, pbits, abits, out_mask, out_idx, out_end, out_pid);
}

// Round 3
// 206.214 us; speedup vs baseline: 1.4341x; 1.4341x over previous
//
#include <hip/hip_runtime.h>
#include <stdint.h>

typedef unsigned long long ull;

#define Bdim 64
#define Tdim 8192
#define MAXP 32
#define NW (Tdim / 64)        // 128 bitmask words per row
#define VOCAB_WORDS_MAX 1024  // >= ceil(50257/64) = 786

// ---------------------------------------------------------------------------
// Kernel 1: detect whether the bool tables are uint8 (raw numpy bool) or
// int32 (harness-widened). Any 32-bit word >1 (or negative) => byte layout.
// ---------------------------------------------------------------------------
__global__ void detect_layout_kernel(const int* __restrict__ p, int nwords,
                                     unsigned long long* __restrict__ flag) {
    __shared__ int s_max;
    if (threadIdx.x == 0) s_max = 0;
    __syncthreads();
    int m = 0;
    for (int i = threadIdx.x; i < nwords; i += blockDim.x) {
        int v = p[i];
        if (v < 0) v = 2;
        if (v > m) m = v;
    }
    atomicMax(&s_max, m);
    __syncthreads();
    if (threadIdx.x == 0) *flag = (s_max > 1) ? 1ull : 0ull;
}

// ---------------------------------------------------------------------------
// Kernel 2: canonicalize both bool tables into bitmasks (1 bit / token).
// ---------------------------------------------------------------------------
__global__ void pack_bits_kernel(const void* __restrict__ punct,
                                 const void* __restrict__ abbr,
                                 int vocab,
                                 const unsigned long long* __restrict__ flag,
                                 unsigned long long* __restrict__ pbits,
                                 unsigned long long* __restrict__ abits,
                                 int nwords) {
    int w = blockIdx.x * blockDim.x + threadIdx.x;
    if (w >= nwords) return;
    bool u8 = (*flag != 0ull);
    unsigned long long pw = 0ull, aw = 0ull;
    int base = w << 6;
    for (int j = 0; j < 64; ++j) {
        int tok = base + j;
        if (tok >= vocab) break;
        bool pv, av;
        if (u8) {
            pv = ((const uint8_t*)punct)[tok] != 0;
            av = ((const uint8_t*)abbr)[tok] != 0;
        } else {
            pv = ((const int*)punct)[tok] != 0;
            av = ((const int*)abbr)[tok] != 0;
        }
        if (pv) pw |= 1ull << j;
        if (av) aw |= 1ull << j;
    }
    pbits[w] = pw;
    abits[w] = aw;
}

// ---------------------------------------------------------------------------
// Kernel A: one block per row. Fully parallel boundary determination.
//   boundary(t) = t<=LR && (base_end(t) || t==LR || (t - prev_anchor)%32==0)
// where prev_anchor = previous base_end position (< t), or -1.
// Writes out_end, out_pid, and per-phrase (first|end<<16) metadata to ws.
// ---------------------------------------------------------------------------
__global__ __launch_bounds__(1024) void phrase_meta_kernel(
    const int* __restrict__ ids,
    const unsigned long long* __restrict__ pbits,
    const unsigned long long* __restrict__ abits,
    int* __restrict__ out_end,    // [B, T]
    int* __restrict__ out_pid,    // [B, T]
    unsigned int* __restrict__ ws_nb,    // [B]
    unsigned int* __restrict__ ws_info)  // [B, T]: first | (end<<16)
{
    __shared__ ull base_bits[NW];
    __shared__ ull end_bits[NW];
    __shared__ int A_pref[NW];   // last base-anchor pos in words < w, or -1
    __shared__ int wpre[NW];     // # end bits in words < w
    __shared__ int E_pref[NW];   // last end-boundary pos in words < w, or -1
    __shared__ int s_last;

    const int b = blockIdx.x;
    const int tid = threadIdx.x;
    const int lane = tid & 63;
    const int wv = tid >> 6;                 // 0..15
    const int* __restrict__ row = ids + (size_t)b * Tdim;
    const size_t rowbase = (size_t)b * Tdim;

    if (tid == 0) s_last = -1;
    __syncthreads();

    // ---- Phase 1: base_end bits (ballot), last_real, out_end = -1 fill ----
    int lmax = -1;
#pragma unroll
    for (int k = 0; k < Tdim / 1024; ++k) {
        int t = k * 1024 + tid;
        int id = row[t];
        bool real = (id != 0);
        bool pu = (pbits[id >> 6] >> (id & 63)) & 1ull;
        bool ab = false;
        if (t > 0) {
            int pv = row[t - 1];
            ab = (abits[pv >> 6] >> (pv & 63)) & 1ull;
        }
        bool be = pu && !ab && real;
        ull bal = __ballot(be);
        if (lane == 0) base_bits[k * 16 + wv] = bal;
        if (real) lmax = t;
        out_end[rowbase + t] = -1;
    }
    for (int off = 32; off; off >>= 1) {
        int o = __shfl_down(lmax, off);
        lmax = o > lmax ? o : lmax;
    }
    if (lane == 0) atomicMax(&s_last, lmax);
    __syncthreads();

    // ---- Scan 1: prefix "last anchor position" over words ----
    if (tid == 0) {
        int run = -1;
#pragma unroll 8
        for (int w = 0; w < NW; ++w) {
            A_pref[w] = run;
            ull x = base_bits[w];
            if (x) run = (w << 6) + 63 - __builtin_clzll(x);
        }
    }
    __syncthreads();

    // ---- Phase 2: boundary bits (ballot) ----
    const int LR = s_last;
#pragma unroll
    for (int k = 0; k < Tdim / 1024; ++k) {
        int t = k * 1024 + tid;
        int w = k * 16 + wv;
        ull bw = base_bits[w];
        ull below = bw & ((1ull << lane) - 1ull);
        int pa = below ? ((w << 6) + 63 - __builtin_clzll(below)) : A_pref[w];
        bool bnd = (t <= LR) &&
                   (((bw >> lane) & 1ull) || (t == LR) || (((t - pa) & 31) == 0));
        ull bal = __ballot(bnd);
        if (lane == 0) end_bits[w] = bal;
    }
    __syncthreads();

    // ---- Scan 2: popcount prefix + prev-boundary prefix ----
    if (tid == 0) {
        int run = -1, cnt = 0;
#pragma unroll 8
        for (int w = 0; w < NW; ++w) {
            wpre[w] = cnt;
            E_pref[w] = run;
            ull x = end_bits[w];
            cnt += __builtin_popcountll(x);
            if (x) run = (w << 6) + 63 - __builtin_clzll(x);
        }
        ws_nb[b] = (unsigned int)cnt;
    }
    __syncthreads();

    // ---- Phase 3: out_pid, per-phrase metadata, out_end overwrite ----
#pragma unroll
    for (int k = 0; k < Tdim / 1024; ++k) {
        int t = k * 1024 + tid;
        int w = k * 16 + wv;
        ull ew = end_bits[w];
        ull below = ew & ((1ull << lane) - 1ull);
        int pid = wpre[w] + __builtin_popcountll(below);
        out_pid[rowbase + t] = pid;
        if ((ew >> lane) & 1ull) {
            int pe = below ? ((w << 6) + 63 - __builtin_clzll(below)) : E_pref[w];
            int first = pe + 1;
            ws_info[(size_t)b * Tdim + pid] =
                (unsigned int)first | ((unsigned int)t << 16);
            out_end[rowbase + pid] = t;
        }
    }
}

// ---------------------------------------------------------------------------
// Kernel B: dense coalesced fill of mask + token_idx (writes final values
// everywhere, replacing memset). 2048 blocks x 256 threads, int4 stores.
// ---------------------------------------------------------------------------
__global__ __launch_bounds__(256) void fill_outputs_kernel(
    const unsigned int* __restrict__ ws_nb,
    const unsigned int* __restrict__ ws_info,
    int4* __restrict__ m4,    // [B * 65536] int4 view of [B,T,32] mask
    int4* __restrict__ i4)    // [B * 65536] int4 view of [B,T,32] idx
{
    const int row = blockIdx.x >> 5;       // 32 blocks per row
    const int seg = blockIdx.x & 31;
    const int nb = (int)ws_nb[row];
    const unsigned int* __restrict__ info = ws_info + (size_t)row * Tdim;
    int4* __restrict__ mrow = m4 + (size_t)row * 65536;
    int4* __restrict__ irow = i4 + (size_t)row * 65536;
#pragma unroll
    for (int i = 0; i < 8; ++i) {
        int g = seg * 2048 + i * 256 + (int)threadIdx.x;  // int4 index in row
        int pid = g >> 3;
        int s0 = (g & 7) << 2;
        int4 mv = {0, 0, 0, 0};
        int4 iv = {0, 0, 0, 0};
        if (pid < nb) {
            unsigned int u = info[pid];
            int first = (int)(u & 0xFFFFu);
            int len = (int)(u >> 16) - first + 1;
            mv.x = (s0 + 0) < len;
            mv.y = (s0 + 1) < len;
            mv.z = (s0 + 2) < len;
            mv.w = (s0 + 3) < len;
            iv.x = (s0 + 0) < len ? first + s0 + 0 : 0;
            iv.y = (s0 + 1) < len ? first + s0 + 1 : 0;
            iv.z = (s0 + 2) < len ? first + s0 + 2 : 0;
            iv.w = (s0 + 3) < len ? first + s0 + 3 : 0;
        }
        mrow[g] = mv;
        irow[g] = iv;
    }
}

// ---------------------------------------------------------------------------
extern "C" void kernel_launch(void* const* d_in, const int* in_sizes, int n_in,
                              void* d_out, int out_size, void* d_ws, size_t ws_size,
                              hipStream_t stream) {
    const int* ids = (const int*)d_in[0];
    const void* punct = d_in[1];
    const void* abbr = d_in[2];
    const int vocab = in_sizes[1];

    int* out = (int*)d_out;
    const size_t maskN = (size_t)Bdim * Tdim * MAXP;   // 16,777,216
    int* out_mask = out;
    int* out_idx  = out + maskN;
    int* out_end  = out + 2 * maskN;
    int* out_pid  = out + 2 * maskN + (size_t)Bdim * Tdim;

    // ws layout: flag(64B) | pbits(8KB) | abits(8KB) | nb(256B) | info(2MB)
    unsigned long long* flag  = (unsigned long long*)d_ws;
    unsigned long long* pbits = (unsigned long long*)((char*)d_ws + 64);
    unsigned long long* abits = pbits + VOCAB_WORDS_MAX;
    unsigned int* ws_nb   = (unsigned int*)(abits + VOCAB_WORDS_MAX);
    unsigned int* ws_info = ws_nb + 64;   // B*T uints = 2 MB

    detect_layout_kernel<<<1, 256, 0, stream>>>((const int*)punct, vocab / 4, flag);

    const int nwords = (vocab + 63) / 64;
    pack_bits_kernel<<<(nwords + 255) / 256, 256, 0, stream>>>(
        punct, abbr, vocab, flag, pbits, abits, nwords);

    phrase_meta_kernel<<<Bdim, 1024, 0, stream>>>(
        ids, pbits, abits, out_end, out_pid, ws_nb, ws_info);

    fill_outputs_kernel<<<Bdim * 32, 256, 0, stream>>>(
        ws_nb, ws_info, (int4*)out_mask, (int4*)out_idx);
}